// Round 15
// baseline (263.757 us; speedup 1.0000x reference)
//
#include <hip/hip_runtime.h>
#include <math.h>

#define NMOL 256
#define NATOM 384
#define NN (NMOL*NATOM)          // 98304
#define A0C  0.529177249f
#define A0_INV (1.0f/0.529177249f)

typedef short bf16x8 __attribute__((ext_vector_type(8)));
typedef float f32x4  __attribute__((ext_vector_type(4)));
typedef _Float16 h16x8 __attribute__((ext_vector_type(8)));

__constant__ float c_sigma[8] = {0.5515909f, 1.8886297f, 1.3225029f, 1.2316629f,
                                 2.1884933f, 1.7750372f, 1.3677907f, 1.3820058f};

__device__ __forceinline__ short f2b(float f) {           // f32 -> bf16 RNE
    unsigned u = __float_as_uint(f);
    u = (u + 0x7fffu + ((u >> 16) & 1u)) >> 16;
    return (short)u;
}
__device__ __forceinline__ float b2f(short s) {
    return __uint_as_float(((unsigned)(unsigned short)s) << 16);
}
// cheap celu(alpha=0.1): 0.1*(e^(10v)-1) = 0.1*exp2(10v*log2e)-0.1
__device__ __forceinline__ float celu01(float v) {
    float e = __builtin_amdgcn_exp2f(v * 14.426950408889634f);
    return v > 0.f ? v : fmaf(0.1f, e, -0.1f);
}
__device__ __forceinline__ bf16x8 cvt8(f32x4 a, f32x4 b) {
    bf16x8 r;
    r[0] = f2b(a.x); r[1] = f2b(a.y); r[2] = f2b(a.z); r[3] = f2b(a.w);
    r[4] = f2b(b.x); r[5] = f2b(b.y); r[6] = f2b(b.z); r[7] = f2b(b.w);
    return r;
}

// fast erf (x>=0): Abramowitz-Stegun 7.1.26, |abs err| <= 1.5e-7
__device__ __forceinline__ float erf_fast(float x) {
    float t = __builtin_amdgcn_rcpf(fmaf(0.3275911f, x, 1.0f));
    float p = fmaf(t, 1.061405429f, -1.453152027f);
    p = fmaf(t, p, 1.421413741f);
    p = fmaf(t, p, -0.284496736f);
    p = fmaf(t, p, 0.254829592f);
    p = p * t;
    float e = __builtin_amdgcn_exp2f(-x * x * 1.4426950408889634f);
    return fmaf(-p, e, 1.0f);
}

// ======================= GEMM0: h1p = aev @ W1a^T + b1 =======================
template<int N, int K>
__global__ __launch_bounds__(256, 4)
void gemm0_k(const float* __restrict__ A, const short* __restrict__ Bw,
             const float* __restrict__ bias, short* __restrict__ Cout)
{
    constexpr int NK = K / 32;
    constexpr int NF = N / 32;
    constexpr int N2 = N / 2;
    constexpr int AROW = 40, BROW = 40;
    constexpr int ASZ = 64 * AROW;
    constexpr int BSZ = N * BROW;
    constexpr int AB  = 2 * ASZ + 2 * BSZ;
    constexpr int CSZ = 64 * N;
    constexpr int SM  = AB > CSZ ? AB : CSZ;
    constexpr int NB  = (N * 4 + 255) / 256;

    __shared__ short smem[SM];
    short* As0 = smem;
    short* As1 = smem + ASZ;
    short* Bs0 = smem + 2 * ASZ;
    short* Bs1 = smem + 2 * ASZ + BSZ;
    short* Cs  = smem;

    const int t    = threadIdx.x;
    const int lane = t & 63;
    const int wave = t >> 6;
    const int wm   = wave >> 1, wn = wave & 1;
    const int l15  = lane & 15, l4 = lane >> 4;
    const int m0   = blockIdx.x * 64;
    const int arow = t >> 2, aseg = t & 3;
    const float* a_f32 = A + ((size_t)m0 + arow) * K + aseg * 8;

    f32x4 af0, af1;
    bf16x8 br[NB];

    auto loadA = [&](int k0) {
        af0 = *(const f32x4*)(a_f32 + k0);
        af1 = *(const f32x4*)(a_f32 + k0 + 4);
    };
    auto loadB = [&](int k0) {
        #pragma unroll
        for (int ci = 0; ci < NB; ++ci) {
            int c = ci * 256 + t;
            if ((N * 4) % 256 == 0 || c < N * 4) {
                int row = c >> 2, half = c & 3;
                br[ci] = *(const bf16x8*)(Bw + (size_t)row * K + k0 + half * 8);
            }
        }
    };
    auto writeA = [&](short* dst) {
        *(bf16x8*)&dst[arow * AROW + aseg * 8] = cvt8(af0, af1);
    };
    auto writeB = [&](short* dst) {
        #pragma unroll
        for (int ci = 0; ci < NB; ++ci) {
            int c = ci * 256 + t;
            if ((N * 4) % 256 == 0 || c < N * 4) {
                int row = c >> 2, half = c & 3;
                *(bf16x8*)&dst[row * BROW + half * 8] = br[ci];
            }
        }
    };

    f32x4 acc[2][NF] = {};

    loadA(0); loadB(0);
    writeA(As0); writeB(Bs0);
    __syncthreads();

    int cur = 0;
    for (int ks = 0; ks < NK; ++ks) {
        if (ks + 1 < NK) { loadA((ks + 1) * 32); loadB((ks + 1) * 32); }
        short* Ac = cur ? As1 : As0;
        short* Bc = cur ? Bs1 : Bs0;
        bf16x8 a[2];
        #pragma unroll
        for (int mf = 0; mf < 2; ++mf)
            a[mf] = *(const bf16x8*)&Ac[(wm * 32 + mf * 16 + l15) * AROW + l4 * 8];
        #pragma unroll
        for (int nf = 0; nf < NF; ++nf) {
            bf16x8 b = *(const bf16x8*)&Bc[(wn * N2 + nf * 16 + l15) * BROW + l4 * 8];
            #pragma unroll
            for (int mf = 0; mf < 2; ++mf)
                acc[mf][nf] = __builtin_amdgcn_mfma_f32_16x16x32_bf16(a[mf], b, acc[mf][nf], 0, 0, 0);
        }
        if (ks + 1 < NK) {
            writeA(cur ? As0 : As1);
            writeB(cur ? Bs0 : Bs1);
            __syncthreads();
            cur ^= 1;
        }
    }
    __syncthreads();

    #pragma unroll
    for (int nf = 0; nf < NF; ++nf) {
        int col = wn * N2 + nf * 16 + l15;
        float bc = bias[col];
        #pragma unroll
        for (int mf = 0; mf < 2; ++mf)
            #pragma unroll
            for (int r = 0; r < 4; ++r)
                Cs[(wm * 32 + mf * 16 + l4 * 4 + r) * N + col] = f2b(acc[mf][nf][r] + bc);
    }
    __syncthreads();
    #pragma unroll
    for (int i = 0; i < NF; ++i) {
        int c = i * 256 + t;
        *(bf16x8*)(Cout + (size_t)m0 * N + c * 8) = *(const bf16x8*)&Cs[c * 8];
    }
}

// ======================= fused layers 2+3+4, BM=128 / 512 threads =======================
// r14's celuA-staged structure with doubled tile: 8 waves = 4 row-groups x 2
// col-halves; per-wave code identical to r14 (same frags, same VGPR); half the
// blocks -> half the prologue/barrier events. (512,2) leaves regalloc free (no
// r10-style spill cap).
__global__ __launch_bounds__(512, 2)
void mlp23_kernel(const short* __restrict__ h1p, const short* __restrict__ W2b,
                  const float* __restrict__ b2, const short* __restrict__ W3b,
                  const float* __restrict__ b3, const float* __restrict__ W4,
                  const float* __restrict__ b4,
                  const float* __restrict__ qv, const float* __restrict__ espv,
                  const float* __restrict__ w1qp, const float* __restrict__ w1ep,
                  const int* __restrict__ species, float* __restrict__ chi)
{
    constexpr int K1 = 160, K2 = 128, N3 = 96;
    constexpr int AROW  = 168;     // celuA stride: 2-way banks (free)
    constexpr int H2ROW = 140;     // H2 stride (aliased into SBUF after barrier)

    __shared__ short SBUF[128 * AROW];         // celuA (stage 1), then H2 (stage 2)
    __shared__ float wq_s[K1], we_s[K1], w4_s[N3], b3_s[N3];
    __shared__ float qrow_s[128], erow_s[128];
    __shared__ float chp[2][128];

    const int t    = threadIdx.x;
    const int lane = t & 63;
    const int wave = t >> 6;
    const int wm   = wave >> 1, wn = wave & 1;   // wm 0..3 (32-row groups), wn 0..1
    const int l15  = lane & 15, l4 = lane >> 4;
    const int m0   = blockIdx.x * 128;

    if (t < K1) { wq_s[t] = w1qp[t]; we_s[t] = w1ep[t]; }
    if (t >= 256 && t < 256 + N3) { w4_s[t - 256] = W4[t - 256]; b3_s[t - 256] = b3[t - 256]; }
    if (t >= 384 && t < 512) {
        int r = t - 384;
        qrow_s[r] = qv[m0 + r];
        erow_s[r] = espv[m0 + r] + espv[NN + m0 + r]
                  + espv[2 * (size_t)NN + m0 + r] + espv[3 * (size_t)NN + m0 + r];
    }
    __syncthreads();   // wq_s/we_s/qrow_s/erow_s visible

    // ---- stage celuA -> SBUF: 128x160 = 2560 8-elem segs, coalesced, celu ONCE ----
    #pragma unroll
    for (int i = 0; i < 5; ++i) {
        int s = t + 512 * i;                   // 0..2559
        int row = s / 20, c8 = s % 20;
        bf16x8 h = *(const bf16x8*)(h1p + ((size_t)m0 + row) * K1 + c8 * 8);
        float qr = qrow_s[row], er = erow_s[row];
        bf16x8 o;
        #pragma unroll
        for (int j = 0; j < 8; ++j) {
            float v = b2f(h[j]) + qr * wq_s[c8 * 8 + j] + er * we_s[c8 * 8 + j];
            o[j] = f2b(celu01(v));
        }
        *(bf16x8*)&SBUF[row * AROW + c8 * 8] = o;
    }
    __syncthreads();   // celuA complete

    // ---- stage 1 MFMA: celuA @ W2^T (K=160), A from LDS, B direct global ----
    f32x4 acc[2][4] = {};
    #pragma unroll
    for (int ks = 0; ks < 5; ++ks) {
        const int k0 = ks * 32 + l4 * 8;
        bf16x8 a[2];
        #pragma unroll
        for (int mf = 0; mf < 2; ++mf)
            a[mf] = *(const bf16x8*)&SBUF[(wm * 32 + mf * 16 + l15) * AROW + k0];
        #pragma unroll
        for (int nf = 0; nf < 4; ++nf) {
            bf16x8 b = *(const bf16x8*)(W2b + (size_t)(wn * 64 + nf * 16 + l15) * K1 + k0);
            #pragma unroll
            for (int mf = 0; mf < 2; ++mf)
                acc[mf][nf] = __builtin_amdgcn_mfma_f32_16x16x32_bf16(a[mf], b, acc[mf][nf], 0, 0, 0);
        }
    }
    __syncthreads();   // all celuA reads done before SBUF is overwritten as H2

    // ---- h2 tile -> SBUF (H2ROW stride, celu applied) ----
    #pragma unroll
    for (int nf = 0; nf < 4; ++nf) {
        int col = wn * 64 + nf * 16 + l15;
        float bc = b2[col];
        #pragma unroll
        for (int mf = 0; mf < 2; ++mf)
            #pragma unroll
            for (int r = 0; r < 4; ++r)
                SBUF[(wm * 32 + mf * 16 + l4 * 4 + r) * H2ROW + col] =
                    f2b(celu01(acc[mf][nf][r] + bc));
    }
    __syncthreads();   // H2 visible

    // ---- stage 2: H2 @ W3^T, K=128, B direct from global ----
    f32x4 acc2[2][3] = {};
    #pragma unroll
    for (int ks = 0; ks < 4; ++ks) {
        bf16x8 a[2];
        #pragma unroll
        for (int mf = 0; mf < 2; ++mf)
            a[mf] = *(const bf16x8*)&SBUF[(wm * 32 + mf * 16 + l15) * H2ROW + ks * 32 + l4 * 8];
        #pragma unroll
        for (int nf = 0; nf < 3; ++nf) {
            bf16x8 b = *(const bf16x8*)(W3b + (size_t)(wn * 48 + nf * 16 + l15) * K2 + ks * 32 + l4 * 8);
            #pragma unroll
            for (int mf = 0; mf < 2; ++mf)
                acc2[mf][nf] = __builtin_amdgcn_mfma_f32_16x16x32_bf16(a[mf], b, acc2[mf][nf], 0, 0, 0);
        }
    }

    // ---- chi epilogue: celu -> .W4 -> lane reduce -> softplus ----
    float val[2][4];
    #pragma unroll
    for (int mf = 0; mf < 2; ++mf)
        #pragma unroll
        for (int r = 0; r < 4; ++r) val[mf][r] = 0.f;
    #pragma unroll
    for (int nf = 0; nf < 3; ++nf) {
        int col = wn * 48 + nf * 16 + l15;
        float bc = b3_s[col];
        float wc = w4_s[col];
        #pragma unroll
        for (int mf = 0; mf < 2; ++mf)
            #pragma unroll
            for (int r = 0; r < 4; ++r)
                val[mf][r] += celu01(acc2[mf][nf][r] + bc) * wc;
    }
    #pragma unroll
    for (int off = 1; off < 16; off <<= 1)
        #pragma unroll
        for (int mf = 0; mf < 2; ++mf)
            #pragma unroll
            for (int r = 0; r < 4; ++r)
                val[mf][r] += __shfl_xor(val[mf][r], off, 64);
    if (l15 == 0) {
        #pragma unroll
        for (int mf = 0; mf < 2; ++mf)
            #pragma unroll
            for (int r = 0; r < 4; ++r)
                chp[wn][wm * 32 + mf * 16 + l4 * 4 + r] = val[mf][r];
    }
    __syncthreads();
    if (t < 128) {
        float s = chp[0][t] + chp[1][t] + b4[0];
        s = fmaxf(s, 0.f) + log1pf(expf(-fabsf(s)));   // softplus
        chi[m0 + t] = (species[m0 + t] != -1) ? s : 0.f;
    }
}

// ============ J-matrix build (iteration-invariant), fp16, masked ============
__global__ __launch_bounds__(384)
void jbuild_kernel(const float* __restrict__ coords, const int* __restrict__ species,
                   _Float16* __restrict__ J)
{
    __shared__ float cx[NATOM], cy[NATOM], cz[NATOM], s2[NATOM], mk[NATOM];
    int m = blockIdx.x, it0 = blockIdx.y * 48;
    int j = threadIdx.x;
    int idx = m * NATOM + j;
    float rx = coords[(size_t)idx * 3 + 0];
    float ry = coords[(size_t)idx * 3 + 1];
    float rz = coords[(size_t)idx * 3 + 2];
    int sp = species[idx];
    float sig = c_sigma[sp < 0 ? 7 : sp];
    cx[j] = rx; cy[j] = ry; cz[j] = rz;
    s2[j] = sig * sig;
    float maskj = (sp != -1) ? 1.f : 0.f;
    mk[j] = maskj;
    __syncthreads();
    float s2j = s2[j];
    #pragma unroll 4
    for (int ii = 0; ii < 48; ++ii) {
        int i = it0 + ii;
        float dx = cx[i] - rx, dy = cy[i] - ry, dz = cz[i] - rz;
        float d2 = fmaf(dx, dx, fmaf(dy, dy, dz * dz)) + 1e-16f;
        float rs = __builtin_amdgcn_rsqf(d2);           // 1/sqrt(d2)
        float d  = d2 * rs * A0_INV;                    // |r|/A0 (Bohr)
        float ss = fmaxf(s2[i] + s2j, 1e-8f);
        float x  = d * __builtin_amdgcn_rsqf(2.f * ss);
        float val = erf_fast(x) * rs * A0C;             // erf(x)/d
        val *= maskj * mk[i];
        val = (i == j) ? 0.f : val;
        J[((size_t)m * NATOM + i) * NATOM + j] = (_Float16)val;
    }
}

// ============ fused charge normalization + ESP matvec partials ============
// DO_MV: grid (NMOL, 4), block 384; plane ic sums i in [ic*96, ic*96+96).
// !DO_MV (final): grid (NMOL, 1); writes output [species | q] directly.
template<bool DO_MV>
__global__ __launch_bounds__(384)
void espmv_kernel(const float* __restrict__ chi, const int* __restrict__ species,
                  const float* __restrict__ netq, const _Float16* __restrict__ J,
                  float* __restrict__ q, float* __restrict__ esp_part,
                  float* __restrict__ out)
{
    __shared__ float pw[6], pwc[6];
    __shared__ float qs[DO_MV ? 96 : 1];
    __shared__ float part[DO_MV ? 8 : 1][DO_MV ? 384 : 1];
    int m = blockIdx.x, ic = blockIdx.y;
    int t = threadIdx.x;
    int lane = t & 63, wv = t >> 6;
    int idx = m * NATOM + t;
    float c = chi[idx];
    int sp = species[idx];
    float mask = (sp != -1) ? 1.f : 0.f;
    float sc = c, sm = mask;
    #pragma unroll
    for (int off = 1; off < 64; off <<= 1) {
        sc += __shfl_xor(sc, off, 64);
        sm += __shfl_xor(sm, off, 64);
    }
    if (lane == 0) { pw[wv] = sc; pwc[wv] = sm; }
    __syncthreads();
    float chi_sum = pw[0] + pw[1] + pw[2] + pw[3] + pw[4] + pw[5];
    float na      = pwc[0] + pwc[1] + pwc[2] + pwc[3] + pwc[4] + pwc[5];
    float Q = netq[m];
    float k_net = 1.f + fabsf(Q) / chi_sum;
    float chi_mean = chi_sum / na;
    float k_p = (Q > 0.f) ? k_net : 1.f;
    float k_n = (Q < 0.f) ? k_net : 1.f;
    float qj = (-k_n * c + k_p * chi_mean) * mask;

    if (!DO_MV) {
        out[idx]      = (float)sp;       // fused output write
        out[NN + idx] = qj;
        return;
    }

    if (ic == 0) q[idx] = qj;            // global q for next iteration's features
    if (t >= ic * 96 && t < ic * 96 + 96) qs[t - ic * 96] = qj;
    __syncthreads();

    int jv = t % 48, isub = t / 48;
    int j0 = jv * 8;
    float acc[8] = {};
    #pragma unroll 4
    for (int k = 0; k < 12; ++k) {
        int il = isub * 12 + k;
        int i = ic * 96 + il;
        h16x8 h = *(const h16x8*)&J[((size_t)m * NATOM + i) * NATOM + j0];
        float qi = qs[il];
        #pragma unroll
        for (int r = 0; r < 8; ++r) acc[r] = fmaf(qi, (float)h[r], acc[r]);
    }
    #pragma unroll
    for (int r = 0; r < 8; ++r) part[isub][j0 + r] = acc[r];
    __syncthreads();
    float s = 0.f;
    #pragma unroll
    for (int g = 0; g < 8; ++g) s += part[g][t];
    esp_part[(size_t)ic * NN + idx] = s;
}

// ============ fallback: direct charge+ESP (ws too small for J) ============
template<bool DO_ESP>
__global__ __launch_bounds__(384)
void espq_kernel(const float* __restrict__ chi, const int* __restrict__ species,
                 const float* __restrict__ netq, const float* __restrict__ coords,
                 float* __restrict__ q, float* __restrict__ esp,
                 float* __restrict__ out)
{
    __shared__ float red[512], redc[512];
    __shared__ float cx[NATOM], cy[NATOM], cz[NATOM], s2[NATOM], qs[NATOM];
    int m = blockIdx.x, j = threadIdx.x;
    int idx = m * NATOM + j;
    float c = chi[idx];
    int sp = species[idx];
    float mask = (sp != -1) ? 1.f : 0.f;
    red[j] = c; redc[j] = mask;
    if (j < 128) { red[NATOM + j] = 0.f; redc[NATOM + j] = 0.f; }
    __syncthreads();
    for (int s = 256; s > 0; s >>= 1) {
        if (j < s) { red[j] += red[j + s]; redc[j] += redc[j + s]; }
        __syncthreads();
    }
    float chi_sum = red[0], na = redc[0];
    float Q = netq[m];
    float k_net = 1.f + fabsf(Q) / chi_sum;
    float chi_mean = chi_sum / na;
    float k_p = (Q > 0.f) ? k_net : 1.f;
    float k_n = (Q < 0.f) ? k_net : 1.f;
    float qj = (-k_n * c + k_p * chi_mean) * mask;

    if (!DO_ESP) {
        out[idx]      = (float)sp;
        out[NN + idx] = qj;
        return;
    }
    q[idx] = qj;

    float rx = coords[(size_t)idx * 3 + 0];
    float ry = coords[(size_t)idx * 3 + 1];
    float rz = coords[(size_t)idx * 3 + 2];
    cx[j] = rx; cy[j] = ry; cz[j] = rz;
    float sig = c_sigma[sp < 0 ? 7 : sp];
    s2[j] = sig * sig;
    qs[j] = qj;
    __syncthreads();
    float s2j = s2[j];
    float acc = 0.f;
    for (int i = 0; i < NATOM; ++i) {
        float dx = cx[i] - rx, dy = cy[i] - ry, dz = cz[i] - rz;
        float d2 = fmaf(dx, dx, fmaf(dy, dy, dz * dz)) + 1e-16f;
        float rs = __builtin_amdgcn_rsqf(d2);
        float d  = d2 * rs * A0_INV;
        float ss = fmaxf(s2[i] + s2j, 1e-8f);
        float x  = d * __builtin_amdgcn_rsqf(2.f * ss);
        float val = erf_fast(x) * rs * A0C;
        acc += (i == j) ? 0.f : qs[i] * val;
    }
    esp[idx] = (mask != 0.f) ? acc : 0.f;
}

// ============ one-time weight conversion to bf16 (+ rank-2 columns) ============
__global__ __launch_bounds__(256)
void wcvt_kernel(const float* __restrict__ W1, const float* __restrict__ W2,
                 const float* __restrict__ W3,
                 short* __restrict__ W1b, short* __restrict__ W2b,
                 short* __restrict__ W3b, float* __restrict__ w1q,
                 float* __restrict__ w1e)
{
    int i = blockIdx.x * 256 + threadIdx.x;
    if (i < 160 * 384) {
        int r = i / 384, cc = i % 384;
        W1b[i] = f2b(W1[(size_t)r * 386 + cc]);
    }
    int j = i - 160 * 384;
    if (j >= 0 && j < 128 * 160) W2b[j] = f2b(W2[j]);
    int k2 = j - 128 * 160;
    if (k2 >= 0 && k2 < 96 * 128) W3b[k2] = f2b(W3[k2]);
    if (i < 160) {
        w1q[i] = W1[(size_t)i * 386 + 384];
        w1e[i] = W1[(size_t)i * 386 + 385];
    }
}

extern "C" void kernel_launch(void* const* d_in, const int* in_sizes, int n_in,
                              void* d_out, int out_size, void* d_ws, size_t ws_size,
                              hipStream_t stream)
{
    const int*   species = (const int*)  d_in[0];
    const float* coords  = (const float*)d_in[1];
    const float* netq    = (const float*)d_in[2];
    const float* aev     = (const float*)d_in[3];
    const float* W1 = (const float*)d_in[4];
    const float* b1 = (const float*)d_in[5];
    const float* W2 = (const float*)d_in[6];
    const float* b2 = (const float*)d_in[7];
    const float* W3 = (const float*)d_in[8];
    const float* b3 = (const float*)d_in[9];
    const float* W4 = (const float*)d_in[10];
    const float* b4 = (const float*)d_in[11];

    float* q    = (float*)d_ws;                 // NN
    float* chi  = q + NN;                       // NN
    float* espp = chi + NN;                     // 4*NN partial planes
    float* w1q  = espp + 4 * (size_t)NN;        // 160
    float* w1e  = w1q + 160;                    // 160
    short* W1b  = (short*)(w1e + 160);          // 160*384
    short* W2b  = W1b + 160 * 384;              // 128*160
    short* W3b  = W2b + 128 * 160;              // 96*128
    short* h1p  = W3b + 96 * 128;               // NN*160 bf16
    _Float16* J = (_Float16*)(h1p + (size_t)NN * 160);  // NN*384 fp16

    const size_t NEED = (size_t)((char*)(J + (size_t)NN * 384) - (char*)d_ws);
    const bool use_J = (ws_size >= NEED);

    // zero q + chi + espp planes (iteration-0 features; fallback keeps planes 1-3 = 0)
    hipMemsetAsync(d_ws, 0, 6 * (size_t)NN * sizeof(float), stream);
    wcvt_kernel<<<(160 * 384 + 128 * 160 + 96 * 128 + 255) / 256, 256, 0, stream>>>(
        W1, W2, W3, W1b, W2b, W3b, w1q, w1e);

    if (use_J)
        jbuild_kernel<<<dim3(NMOL, 8), 384, 0, stream>>>(coords, species, J);

    // iteration-invariant: h1p = aev @ W1[:, :384]^T + b1
    gemm0_k<160, 384><<<NN / 64, 256, 0, stream>>>(aev, W1b, b1, h1p);

    for (int it = 0; it < 4; ++it) {
        mlp23_kernel<<<NN / 128, 512, 0, stream>>>(
            h1p, W2b, b2, W3b, b3, W4, b4, q, espp, w1q, w1e, species, chi);
        if (use_J) {
            if (it < 3)
                espmv_kernel<true><<<dim3(NMOL, 4), 384, 0, stream>>>(
                    chi, species, netq, J, q, espp, nullptr);
            else
                espmv_kernel<false><<<dim3(NMOL, 1), 384, 0, stream>>>(
                    chi, species, netq, J, q, espp, (float*)d_out);
        } else {
            if (it < 3)
                espq_kernel<true><<<NMOL, 384, 0, stream>>>(
                    chi, species, netq, coords, q, espp, nullptr);
            else
                espq_kernel<false><<<NMOL, 384, 0, stream>>>(
                    chi, species, netq, coords, q, espp, (float*)d_out);
        }
    }
}

// Round 16
// 251.001 us; speedup vs baseline: 1.0508x; 1.0508x over previous
//
#include <hip/hip_runtime.h>
#include <math.h>

#define NMOL 256
#define NATOM 384
#define NN (NMOL*NATOM)          // 98304
#define A0C  0.529177249f
#define A0_INV (1.0f/0.529177249f)

typedef short bf16x8 __attribute__((ext_vector_type(8)));
typedef float f32x4  __attribute__((ext_vector_type(4)));
typedef _Float16 h16x8 __attribute__((ext_vector_type(8)));

__constant__ float c_sigma[8] = {0.5515909f, 1.8886297f, 1.3225029f, 1.2316629f,
                                 2.1884933f, 1.7750372f, 1.3677907f, 1.3820058f};

__device__ __forceinline__ short f2b(float f) {           // f32 -> bf16 RNE
    unsigned u = __float_as_uint(f);
    u = (u + 0x7fffu + ((u >> 16) & 1u)) >> 16;
    return (short)u;
}
__device__ __forceinline__ float b2f(short s) {
    return __uint_as_float(((unsigned)(unsigned short)s) << 16);
}
// cheap celu(alpha=0.1): 0.1*(e^(10v)-1) = 0.1*exp2(10v*log2e)-0.1
__device__ __forceinline__ float celu01(float v) {
    float e = __builtin_amdgcn_exp2f(v * 14.426950408889634f);
    return v > 0.f ? v : fmaf(0.1f, e, -0.1f);
}
__device__ __forceinline__ bf16x8 cvt8(f32x4 a, f32x4 b) {
    bf16x8 r;
    r[0] = f2b(a.x); r[1] = f2b(a.y); r[2] = f2b(a.z); r[3] = f2b(a.w);
    r[4] = f2b(b.x); r[5] = f2b(b.y); r[6] = f2b(b.z); r[7] = f2b(b.w);
    return r;
}

// fast erf (x>=0): Abramowitz-Stegun 7.1.26, |abs err| <= 1.5e-7
__device__ __forceinline__ float erf_fast(float x) {
    float t = __builtin_amdgcn_rcpf(fmaf(0.3275911f, x, 1.0f));
    float p = fmaf(t, 1.061405429f, -1.453152027f);
    p = fmaf(t, p, 1.421413741f);
    p = fmaf(t, p, -0.284496736f);
    p = fmaf(t, p, 0.254829592f);
    p = p * t;
    float e = __builtin_amdgcn_exp2f(-x * x * 1.4426950408889634f);
    return fmaf(-p, e, 1.0f);
}

// ======================= GEMM0: h1p = aev @ W1a^T + b1 =======================
template<int N, int K>
__global__ __launch_bounds__(256, 4)
void gemm0_k(const float* __restrict__ A, const short* __restrict__ Bw,
             const float* __restrict__ bias, short* __restrict__ Cout)
{
    constexpr int NK = K / 32;
    constexpr int NF = N / 32;
    constexpr int N2 = N / 2;
    constexpr int AROW = 40, BROW = 40;
    constexpr int ASZ = 64 * AROW;
    constexpr int BSZ = N * BROW;
    constexpr int AB  = 2 * ASZ + 2 * BSZ;
    constexpr int CSZ = 64 * N;
    constexpr int SM  = AB > CSZ ? AB : CSZ;
    constexpr int NB  = (N * 4 + 255) / 256;

    __shared__ short smem[SM];
    short* As0 = smem;
    short* As1 = smem + ASZ;
    short* Bs0 = smem + 2 * ASZ;
    short* Bs1 = smem + 2 * ASZ + BSZ;
    short* Cs  = smem;

    const int t    = threadIdx.x;
    const int lane = t & 63;
    const int wave = t >> 6;
    const int wm   = wave >> 1, wn = wave & 1;
    const int l15  = lane & 15, l4 = lane >> 4;
    const int m0   = blockIdx.x * 64;
    const int arow = t >> 2, aseg = t & 3;
    const float* a_f32 = A + ((size_t)m0 + arow) * K + aseg * 8;

    f32x4 af0, af1;
    bf16x8 br[NB];

    auto loadA = [&](int k0) {
        af0 = *(const f32x4*)(a_f32 + k0);
        af1 = *(const f32x4*)(a_f32 + k0 + 4);
    };
    auto loadB = [&](int k0) {
        #pragma unroll
        for (int ci = 0; ci < NB; ++ci) {
            int c = ci * 256 + t;
            if ((N * 4) % 256 == 0 || c < N * 4) {
                int row = c >> 2, half = c & 3;
                br[ci] = *(const bf16x8*)(Bw + (size_t)row * K + k0 + half * 8);
            }
        }
    };
    auto writeA = [&](short* dst) {
        *(bf16x8*)&dst[arow * AROW + aseg * 8] = cvt8(af0, af1);
    };
    auto writeB = [&](short* dst) {
        #pragma unroll
        for (int ci = 0; ci < NB; ++ci) {
            int c = ci * 256 + t;
            if ((N * 4) % 256 == 0 || c < N * 4) {
                int row = c >> 2, half = c & 3;
                *(bf16x8*)&dst[row * BROW + half * 8] = br[ci];
            }
        }
    };

    f32x4 acc[2][NF] = {};

    loadA(0); loadB(0);
    writeA(As0); writeB(Bs0);
    __syncthreads();

    int cur = 0;
    for (int ks = 0; ks < NK; ++ks) {
        if (ks + 1 < NK) { loadA((ks + 1) * 32); loadB((ks + 1) * 32); }
        short* Ac = cur ? As1 : As0;
        short* Bc = cur ? Bs1 : Bs0;
        bf16x8 a[2];
        #pragma unroll
        for (int mf = 0; mf < 2; ++mf)
            a[mf] = *(const bf16x8*)&Ac[(wm * 32 + mf * 16 + l15) * AROW + l4 * 8];
        #pragma unroll
        for (int nf = 0; nf < NF; ++nf) {
            bf16x8 b = *(const bf16x8*)&Bc[(wn * N2 + nf * 16 + l15) * BROW + l4 * 8];
            #pragma unroll
            for (int mf = 0; mf < 2; ++mf)
                acc[mf][nf] = __builtin_amdgcn_mfma_f32_16x16x32_bf16(a[mf], b, acc[mf][nf], 0, 0, 0);
        }
        if (ks + 1 < NK) {
            writeA(cur ? As0 : As1);
            writeB(cur ? Bs0 : Bs1);
            __syncthreads();
            cur ^= 1;
        }
    }
    __syncthreads();

    #pragma unroll
    for (int nf = 0; nf < NF; ++nf) {
        int col = wn * N2 + nf * 16 + l15;
        float bc = bias[col];
        #pragma unroll
        for (int mf = 0; mf < 2; ++mf)
            #pragma unroll
            for (int r = 0; r < 4; ++r)
                Cs[(wm * 32 + mf * 16 + l4 * 4 + r) * N + col] = f2b(acc[mf][nf][r] + bc);
    }
    __syncthreads();
    #pragma unroll
    for (int i = 0; i < NF; ++i) {
        int c = i * 256 + t;
        *(bf16x8*)(Cout + (size_t)m0 * N + c * 8) = *(const bf16x8*)&Cs[c * 8];
    }
}

// ======================= fused layers 2+3+4, celuA staged in LDS once =======================
// r14 proven-best config (251.3us): BM=64, 256 thr, (256,4). celuA computed ONCE
// by a cooperative coalesced pass into SBUF; 2x2 wave MFMA; B direct-from-global;
// H2 aliases SBUF. r15's BM=128/512-thr variant regressed (2 blocks/CU).
__global__ __launch_bounds__(256, 4)
void mlp23_kernel(const short* __restrict__ h1p, const short* __restrict__ W2b,
                  const float* __restrict__ b2, const short* __restrict__ W3b,
                  const float* __restrict__ b3, const float* __restrict__ W4,
                  const float* __restrict__ b4,
                  const float* __restrict__ qv, const float* __restrict__ espv,
                  const float* __restrict__ w1qp, const float* __restrict__ w1ep,
                  const int* __restrict__ species, float* __restrict__ chi)
{
    constexpr int K1 = 160, K2 = 128, N3 = 96;
    constexpr int AROW  = 168;     // celuA stride: 2-way banks (free)
    constexpr int H2ROW = 140;     // H2 stride (aliased into SBUF after barrier)

    __shared__ short SBUF[64 * AROW];          // celuA (stage 1), then H2 (stage 2)
    __shared__ float wq_s[K1], we_s[K1], w4_s[N3], b3_s[N3];
    __shared__ float qrow_s[64], erow_s[64];
    __shared__ float chp[2][64];

    const int t    = threadIdx.x;
    const int lane = t & 63;
    const int wave = t >> 6;
    const int wm   = wave >> 1, wn = wave & 1;
    const int l15  = lane & 15, l4 = lane >> 4;
    const int m0   = blockIdx.x * 64;

    if (t < K1) { wq_s[t] = w1qp[t]; we_s[t] = w1ep[t]; }
    if (t < N3) { w4_s[t] = W4[t]; b3_s[t] = b3[t]; }
    if (t < 64) {
        qrow_s[t] = qv[m0 + t];
        erow_s[t] = espv[m0 + t] + espv[NN + m0 + t]
                  + espv[2 * (size_t)NN + m0 + t] + espv[3 * (size_t)NN + m0 + t];
    }
    __syncthreads();   // wq_s/we_s/qrow_s/erow_s visible

    // ---- stage celuA -> SBUF: 64x160 = 1280 8-elem segs, coalesced, celu ONCE ----
    #pragma unroll
    for (int i = 0; i < 5; ++i) {
        int s = t + 256 * i;                   // 0..1279
        int row = s / 20, c8 = s % 20;
        bf16x8 h = *(const bf16x8*)(h1p + ((size_t)m0 + row) * K1 + c8 * 8);
        float qr = qrow_s[row], er = erow_s[row];
        bf16x8 o;
        #pragma unroll
        for (int j = 0; j < 8; ++j) {
            float v = b2f(h[j]) + qr * wq_s[c8 * 8 + j] + er * we_s[c8 * 8 + j];
            o[j] = f2b(celu01(v));
        }
        *(bf16x8*)&SBUF[row * AROW + c8 * 8] = o;
    }
    __syncthreads();   // celuA complete

    // ---- stage 1 MFMA: celuA @ W2^T (K=160), A from LDS, B direct global ----
    f32x4 acc[2][4] = {};
    #pragma unroll
    for (int ks = 0; ks < 5; ++ks) {
        const int k0 = ks * 32 + l4 * 8;
        bf16x8 a[2];
        #pragma unroll
        for (int mf = 0; mf < 2; ++mf)
            a[mf] = *(const bf16x8*)&SBUF[(wm * 32 + mf * 16 + l15) * AROW + k0];
        #pragma unroll
        for (int nf = 0; nf < 4; ++nf) {
            bf16x8 b = *(const bf16x8*)(W2b + (size_t)(wn * 64 + nf * 16 + l15) * K1 + k0);
            #pragma unroll
            for (int mf = 0; mf < 2; ++mf)
                acc[mf][nf] = __builtin_amdgcn_mfma_f32_16x16x32_bf16(a[mf], b, acc[mf][nf], 0, 0, 0);
        }
    }
    __syncthreads();   // all celuA reads done before SBUF is overwritten as H2

    // ---- h2 tile -> SBUF (H2ROW stride, celu applied) ----
    #pragma unroll
    for (int nf = 0; nf < 4; ++nf) {
        int col = wn * 64 + nf * 16 + l15;
        float bc = b2[col];
        #pragma unroll
        for (int mf = 0; mf < 2; ++mf)
            #pragma unroll
            for (int r = 0; r < 4; ++r)
                SBUF[(wm * 32 + mf * 16 + l4 * 4 + r) * H2ROW + col] =
                    f2b(celu01(acc[mf][nf][r] + bc));
    }
    __syncthreads();   // H2 visible

    // ---- stage 2: H2 @ W3^T, K=128, B direct from global ----
    f32x4 acc2[2][3] = {};
    #pragma unroll
    for (int ks = 0; ks < 4; ++ks) {
        bf16x8 a[2];
        #pragma unroll
        for (int mf = 0; mf < 2; ++mf)
            a[mf] = *(const bf16x8*)&SBUF[(wm * 32 + mf * 16 + l15) * H2ROW + ks * 32 + l4 * 8];
        #pragma unroll
        for (int nf = 0; nf < 3; ++nf) {
            bf16x8 b = *(const bf16x8*)(W3b + (size_t)(wn * 48 + nf * 16 + l15) * K2 + ks * 32 + l4 * 8);
            #pragma unroll
            for (int mf = 0; mf < 2; ++mf)
                acc2[mf][nf] = __builtin_amdgcn_mfma_f32_16x16x32_bf16(a[mf], b, acc2[mf][nf], 0, 0, 0);
        }
    }

    // ---- chi epilogue: celu -> .W4 -> lane reduce -> softplus ----
    float val[2][4];
    #pragma unroll
    for (int mf = 0; mf < 2; ++mf)
        #pragma unroll
        for (int r = 0; r < 4; ++r) val[mf][r] = 0.f;
    #pragma unroll
    for (int nf = 0; nf < 3; ++nf) {
        int col = wn * 48 + nf * 16 + l15;
        float bc = b3_s[col];
        float wc = w4_s[col];
        #pragma unroll
        for (int mf = 0; mf < 2; ++mf)
            #pragma unroll
            for (int r = 0; r < 4; ++r)
                val[mf][r] += celu01(acc2[mf][nf][r] + bc) * wc;
    }
    #pragma unroll
    for (int off = 1; off < 16; off <<= 1)
        #pragma unroll
        for (int mf = 0; mf < 2; ++mf)
            #pragma unroll
            for (int r = 0; r < 4; ++r)
                val[mf][r] += __shfl_xor(val[mf][r], off, 64);
    if (l15 == 0) {
        #pragma unroll
        for (int mf = 0; mf < 2; ++mf)
            #pragma unroll
            for (int r = 0; r < 4; ++r)
                chp[wn][wm * 32 + mf * 16 + l4 * 4 + r] = val[mf][r];
    }
    __syncthreads();
    if (t < 64) {
        float s = chp[0][t] + chp[1][t] + b4[0];
        s = fmaxf(s, 0.f) + log1pf(expf(-fabsf(s)));   // softplus
        chi[m0 + t] = (species[m0 + t] != -1) ? s : 0.f;
    }
}

// ============ J-matrix build (iteration-invariant), fp16, masked ============
__global__ __launch_bounds__(384)
void jbuild_kernel(const float* __restrict__ coords, const int* __restrict__ species,
                   _Float16* __restrict__ J)
{
    __shared__ float cx[NATOM], cy[NATOM], cz[NATOM], s2[NATOM], mk[NATOM];
    int m = blockIdx.x, it0 = blockIdx.y * 48;
    int j = threadIdx.x;
    int idx = m * NATOM + j;
    float rx = coords[(size_t)idx * 3 + 0];
    float ry = coords[(size_t)idx * 3 + 1];
    float rz = coords[(size_t)idx * 3 + 2];
    int sp = species[idx];
    float sig = c_sigma[sp < 0 ? 7 : sp];
    cx[j] = rx; cy[j] = ry; cz[j] = rz;
    s2[j] = sig * sig;
    float maskj = (sp != -1) ? 1.f : 0.f;
    mk[j] = maskj;
    __syncthreads();
    float s2j = s2[j];
    #pragma unroll 4
    for (int ii = 0; ii < 48; ++ii) {
        int i = it0 + ii;
        float dx = cx[i] - rx, dy = cy[i] - ry, dz = cz[i] - rz;
        float d2 = fmaf(dx, dx, fmaf(dy, dy, dz * dz)) + 1e-16f;
        float rs = __builtin_amdgcn_rsqf(d2);           // 1/sqrt(d2)
        float d  = d2 * rs * A0_INV;                    // |r|/A0 (Bohr)
        float ss = fmaxf(s2[i] + s2j, 1e-8f);
        float x  = d * __builtin_amdgcn_rsqf(2.f * ss);
        float val = erf_fast(x) * rs * A0C;             // erf(x)/d
        val *= maskj * mk[i];
        val = (i == j) ? 0.f : val;
        J[((size_t)m * NATOM + i) * NATOM + j] = (_Float16)val;
    }
}

// ============ fused charge normalization + ESP matvec partials ============
// DO_MV: grid (NMOL, 4), block 384; plane ic sums i in [ic*96, ic*96+96).
// !DO_MV (final): grid (NMOL, 1); writes output [species | q] directly.
template<bool DO_MV>
__global__ __launch_bounds__(384)
void espmv_kernel(const float* __restrict__ chi, const int* __restrict__ species,
                  const float* __restrict__ netq, const _Float16* __restrict__ J,
                  float* __restrict__ q, float* __restrict__ esp_part,
                  float* __restrict__ out)
{
    __shared__ float pw[6], pwc[6];
    __shared__ float qs[DO_MV ? 96 : 1];
    __shared__ float part[DO_MV ? 8 : 1][DO_MV ? 384 : 1];
    int m = blockIdx.x, ic = blockIdx.y;
    int t = threadIdx.x;
    int lane = t & 63, wv = t >> 6;
    int idx = m * NATOM + t;
    float c = chi[idx];
    int sp = species[idx];
    float mask = (sp != -1) ? 1.f : 0.f;
    float sc = c, sm = mask;
    #pragma unroll
    for (int off = 1; off < 64; off <<= 1) {
        sc += __shfl_xor(sc, off, 64);
        sm += __shfl_xor(sm, off, 64);
    }
    if (lane == 0) { pw[wv] = sc; pwc[wv] = sm; }
    __syncthreads();
    float chi_sum = pw[0] + pw[1] + pw[2] + pw[3] + pw[4] + pw[5];
    float na      = pwc[0] + pwc[1] + pwc[2] + pwc[3] + pwc[4] + pwc[5];
    float Q = netq[m];
    float k_net = 1.f + fabsf(Q) / chi_sum;
    float chi_mean = chi_sum / na;
    float k_p = (Q > 0.f) ? k_net : 1.f;
    float k_n = (Q < 0.f) ? k_net : 1.f;
    float qj = (-k_n * c + k_p * chi_mean) * mask;

    if (!DO_MV) {
        out[idx]      = (float)sp;       // fused output write
        out[NN + idx] = qj;
        return;
    }

    if (ic == 0) q[idx] = qj;            // global q for next iteration's features
    if (t >= ic * 96 && t < ic * 96 + 96) qs[t - ic * 96] = qj;
    __syncthreads();

    int jv = t % 48, isub = t / 48;
    int j0 = jv * 8;
    float acc[8] = {};
    #pragma unroll 4
    for (int k = 0; k < 12; ++k) {
        int il = isub * 12 + k;
        int i = ic * 96 + il;
        h16x8 h = *(const h16x8*)&J[((size_t)m * NATOM + i) * NATOM + j0];
        float qi = qs[il];
        #pragma unroll
        for (int r = 0; r < 8; ++r) acc[r] = fmaf(qi, (float)h[r], acc[r]);
    }
    #pragma unroll
    for (int r = 0; r < 8; ++r) part[isub][j0 + r] = acc[r];
    __syncthreads();
    float s = 0.f;
    #pragma unroll
    for (int g = 0; g < 8; ++g) s += part[g][t];
    esp_part[(size_t)ic * NN + idx] = s;
}

// ============ fallback: direct charge+ESP (ws too small for J) ============
template<bool DO_ESP>
__global__ __launch_bounds__(384)
void espq_kernel(const float* __restrict__ chi, const int* __restrict__ species,
                 const float* __restrict__ netq, const float* __restrict__ coords,
                 float* __restrict__ q, float* __restrict__ esp,
                 float* __restrict__ out)
{
    __shared__ float red[512], redc[512];
    __shared__ float cx[NATOM], cy[NATOM], cz[NATOM], s2[NATOM], qs[NATOM];
    int m = blockIdx.x, j = threadIdx.x;
    int idx = m * NATOM + j;
    float c = chi[idx];
    int sp = species[idx];
    float mask = (sp != -1) ? 1.f : 0.f;
    red[j] = c; redc[j] = mask;
    if (j < 128) { red[NATOM + j] = 0.f; redc[NATOM + j] = 0.f; }
    __syncthreads();
    for (int s = 256; s > 0; s >>= 1) {
        if (j < s) { red[j] += red[j + s]; redc[j] += redc[j + s]; }
        __syncthreads();
    }
    float chi_sum = red[0], na = redc[0];
    float Q = netq[m];
    float k_net = 1.f + fabsf(Q) / chi_sum;
    float chi_mean = chi_sum / na;
    float k_p = (Q > 0.f) ? k_net : 1.f;
    float k_n = (Q < 0.f) ? k_net : 1.f;
    float qj = (-k_n * c + k_p * chi_mean) * mask;

    if (!DO_ESP) {
        out[idx]      = (float)sp;
        out[NN + idx] = qj;
        return;
    }
    q[idx] = qj;

    float rx = coords[(size_t)idx * 3 + 0];
    float ry = coords[(size_t)idx * 3 + 1];
    float rz = coords[(size_t)idx * 3 + 2];
    cx[j] = rx; cy[j] = ry; cz[j] = rz;
    float sig = c_sigma[sp < 0 ? 7 : sp];
    s2[j] = sig * sig;
    qs[j] = qj;
    __syncthreads();
    float s2j = s2[j];
    float acc = 0.f;
    for (int i = 0; i < NATOM; ++i) {
        float dx = cx[i] - rx, dy = cy[i] - ry, dz = cz[i] - rz;
        float d2 = fmaf(dx, dx, fmaf(dy, dy, dz * dz)) + 1e-16f;
        float rs = __builtin_amdgcn_rsqf(d2);
        float d  = d2 * rs * A0_INV;
        float ss = fmaxf(s2[i] + s2j, 1e-8f);
        float x  = d * __builtin_amdgcn_rsqf(2.f * ss);
        float val = erf_fast(x) * rs * A0C;
        acc += (i == j) ? 0.f : qs[i] * val;
    }
    esp[idx] = (mask != 0.f) ? acc : 0.f;
}

// ============ one-time weight conversion to bf16 (+ rank-2 columns) ============
__global__ __launch_bounds__(256)
void wcvt_kernel(const float* __restrict__ W1, const float* __restrict__ W2,
                 const float* __restrict__ W3,
                 short* __restrict__ W1b, short* __restrict__ W2b,
                 short* __restrict__ W3b, float* __restrict__ w1q,
                 float* __restrict__ w1e)
{
    int i = blockIdx.x * 256 + threadIdx.x;
    if (i < 160 * 384) {
        int r = i / 384, cc = i % 384;
        W1b[i] = f2b(W1[(size_t)r * 386 + cc]);
    }
    int j = i - 160 * 384;
    if (j >= 0 && j < 128 * 160) W2b[j] = f2b(W2[j]);
    int k2 = j - 128 * 160;
    if (k2 >= 0 && k2 < 96 * 128) W3b[k2] = f2b(W3[k2]);
    if (i < 160) {
        w1q[i] = W1[(size_t)i * 386 + 384];
        w1e[i] = W1[(size_t)i * 386 + 385];
    }
}

extern "C" void kernel_launch(void* const* d_in, const int* in_sizes, int n_in,
                              void* d_out, int out_size, void* d_ws, size_t ws_size,
                              hipStream_t stream)
{
    const int*   species = (const int*)  d_in[0];
    const float* coords  = (const float*)d_in[1];
    const float* netq    = (const float*)d_in[2];
    const float* aev     = (const float*)d_in[3];
    const float* W1 = (const float*)d_in[4];
    const float* b1 = (const float*)d_in[5];
    const float* W2 = (const float*)d_in[6];
    const float* b2 = (const float*)d_in[7];
    const float* W3 = (const float*)d_in[8];
    const float* b3 = (const float*)d_in[9];
    const float* W4 = (const float*)d_in[10];
    const float* b4 = (const float*)d_in[11];

    float* q    = (float*)d_ws;                 // NN
    float* chi  = q + NN;                       // NN
    float* espp = chi + NN;                     // 4*NN partial planes
    float* w1q  = espp + 4 * (size_t)NN;        // 160
    float* w1e  = w1q + 160;                    // 160
    short* W1b  = (short*)(w1e + 160);          // 160*384
    short* W2b  = W1b + 160 * 384;              // 128*160
    short* W3b  = W2b + 128 * 160;              // 96*128
    short* h1p  = W3b + 96 * 128;               // NN*160 bf16
    _Float16* J = (_Float16*)(h1p + (size_t)NN * 160);  // NN*384 fp16

    const size_t NEED = (size_t)((char*)(J + (size_t)NN * 384) - (char*)d_ws);
    const bool use_J = (ws_size >= NEED);

    // zero q + chi + espp planes (iteration-0 features; fallback keeps planes 1-3 = 0)
    hipMemsetAsync(d_ws, 0, 6 * (size_t)NN * sizeof(float), stream);
    wcvt_kernel<<<(160 * 384 + 128 * 160 + 96 * 128 + 255) / 256, 256, 0, stream>>>(
        W1, W2, W3, W1b, W2b, W3b, w1q, w1e);

    if (use_J)
        jbuild_kernel<<<dim3(NMOL, 8), 384, 0, stream>>>(coords, species, J);

    // iteration-invariant: h1p = aev @ W1[:, :384]^T + b1
    gemm0_k<160, 384><<<NN / 64, 256, 0, stream>>>(aev, W1b, b1, h1p);

    for (int it = 0; it < 4; ++it) {
        mlp23_kernel<<<NN / 64, 256, 0, stream>>>(
            h1p, W2b, b2, W3b, b3, W4, b4, q, espp, w1q, w1e, species, chi);
        if (use_J) {
            if (it < 3)
                espmv_kernel<true><<<dim3(NMOL, 4), 384, 0, stream>>>(
                    chi, species, netq, J, q, espp, nullptr);
            else
                espmv_kernel<false><<<dim3(NMOL, 1), 384, 0, stream>>>(
                    chi, species, netq, J, q, espp, (float*)d_out);
        } else {
            if (it < 3)
                espq_kernel<true><<<NMOL, 384, 0, stream>>>(
                    chi, species, netq, coords, q, espp, nullptr);
            else
                espq_kernel<false><<<NMOL, 384, 0, stream>>>(
                    chi, species, netq, coords, q, espp, (float*)d_out);
        }
    }
}